// Round 1
// baseline (212.313 us; speedup 1.0000x reference)
//
#include <hip/hip_runtime.h>
#include <math.h>

#define NB  32
#define NKC 128
#define DH  64
#define NEX 1024
#define G3  192

// ws layout (floats)
#define GIOFF   0         // 32*192  = 6144
#define KCIOFF  6144      // 32*128  = 4096
#define KCGOFF  10240     // 128*128 = 16384
#define EPOFF   26624     // 128*64  = 8192
#define NHOFF   34816     // 32*128*64 = 262144
#define DPOFF   296960    // 32*128*64 = 262144  (end = 559104 floats = 2.24 MB)

__device__ __forceinline__ float sigf(float x) { return 1.0f / (1.0f + expf(-x)); }

// ---------------------------------------------------------------------------
// K1: per-b x, gi, kci; plus kc_graph=sigmoid(kc_gamma); plus epart.
// grid = 37 blocks x 256 threads. blocks 0..31: batch b; 32: kcg; 33..36: epart
// ---------------------------------------------------------------------------
__global__ __launch_bounds__(256) void k1_prep(
    const float* __restrict__ ex, const float* __restrict__ su,
    const float* __restrict__ ex_graph, const float* __restrict__ kc_gamma,
    const float* __restrict__ W_ex, const float* __restrict__ W_kc,
    const float* __restrict__ tgru_wih, const float* __restrict__ tgru_bih,
    const float* __restrict__ fpart_w, const float* __restrict__ fpart_b,
    float* __restrict__ ws)
{
    int t = threadIdx.x;
    int blk = blockIdx.x;
    if (blk < NB) {
        __shared__ float exs[NEX];
        __shared__ float xl[DH];
        __shared__ float kred[256];
        int b = blk;
        const float* exb = ex + (size_t)b * NEX;
        // stage ex[b] (coalesced float4)
        {
            int idx = t * 4;
            *(float4*)&exs[idx] = *(const float4*)&exb[idx];
        }
        __syncthreads();
        float sub = su[b];
        int wave = t >> 6, lane = t & 63;
        // x[b,d] = su*dot(ex, W_ex[d,0:1024]) + (1-su)*dot(ex, W_ex[d,1024:2048])
        for (int m = 0; m < 16; ++m) {
            int d = wave * 16 + m;
            const float* wrow = W_ex + (size_t)d * (2 * NEX);
            float a1 = 0.f, a2 = 0.f;
            for (int k = lane; k < NEX; k += 64) {
                a1 = fmaf(exs[k], wrow[k], a1);
                a2 = fmaf(exs[k], wrow[NEX + k], a2);
            }
            float v = sub * a1 + (1.0f - sub) * a2;
            #pragma unroll
            for (int off = 32; off; off >>= 1) v += __shfl_down(v, off, 64);
            if (lane == 0) xl[d] = v;
        }
        // kci[b,i] = dot(ex[b], ex_graph[:,i]) — 2 threads per i
        {
            int i = t & 127, half = t >> 7;
            const float* eg = ex_graph + (size_t)(half * 512) * NKC + i;
            int kb = half * 512;
            float a = 0.f;
            for (int k = 0; k < 512; ++k) a = fmaf(exs[kb + k], eg[(size_t)k * NKC], a);
            kred[t] = a;
        }
        __syncthreads();
        if (t < NKC) ws[KCIOFF + b * NKC + t] = kred[t] + kred[t + 128];
        // gi[b,g] = dot(x, tgru_wih[g,:]) + bih[g]  (shared by all 128 KC!)
        if (t < G3) {
            const float* wr = tgru_wih + t * DH;
            float a = tgru_bih[t];
            for (int k = 0; k < DH; ++k) a = fmaf(xl[k], wr[k], a);
            ws[GIOFF + b * G3 + t] = a;
        }
    } else if (blk == NB) {
        for (int idx = t; idx < NKC * NKC; idx += 256)
            ws[KCGOFF + idx] = sigf(kc_gamma[idx]);
    } else {
        // epart[j,d] = sum_c W_kc[c,j]*fpart_w[d,64+c] + fpart_b[d]
        int eb = blk - (NB + 1);  // 0..3
        for (int m = 0; m < 8; ++m) {
            int idx = eb * 2048 + m * 256 + t;
            int j = idx >> 6, d = idx & 63;
            float a = fpart_b[d];
            const float* fw = fpart_w + d * 128 + 64;
            const float* wk = W_kc + j;
            for (int c = 0; c < 64; ++c) a = fmaf(wk[(size_t)c * NKC], fw[c], a);
            ws[EPOFF + idx] = a;
        }
    }
}

// ---------------------------------------------------------------------------
// K2: tgru cell + new_h + dpart. grid = 128 blocks (b x 4 i-chunks of 32).
// wave handles 8 i; whh staged transposed in LDS (k-chunked, stride 193).
// ---------------------------------------------------------------------------
__global__ __launch_bounds__(256) void k2_tgru(
    const float* __restrict__ h, const float* __restrict__ tgru_whh,
    const float* __restrict__ tgru_bhh, const float* __restrict__ fpart_w,
    float* __restrict__ ws)
{
    int t = threadIdx.x, wave = t >> 6, lane = t & 63;
    int b = blockIdx.x >> 2;
    int i0 = (blockIdx.x & 3) * 32;
    __shared__ float wbuf[32 * 193];   // whh^T chunk; reused for fpart_w^T (64*65)
    __shared__ float ht[32 * DH];
    __shared__ float dlt[32 * DH];
    __shared__ float gis[G3];
    __shared__ float bhs[G3];
    __shared__ float kcis[32];

    const float* hb = h + (size_t)(b * NKC + i0) * DH;
    for (int idx = t; idx < 32 * DH; idx += 256) ht[idx] = hb[idx];
    if (t < G3) { gis[t] = ws[GIOFF + b * G3 + t]; bhs[t] = tgru_bhh[t]; }
    if (t < 32) kcis[t] = ws[KCIOFF + b * NKC + i0 + t];

    float ar[8], az[8], an[8];
    #pragma unroll
    for (int m = 0; m < 8; ++m) { ar[m] = 0.f; az[m] = 0.f; an[m] = 0.f; }

    for (int ch = 0; ch < 2; ++ch) {
        __syncthreads();
        for (int idx = t; idx < G3 * 32; idx += 256) {
            int row = idx >> 5, kk = idx & 31;
            wbuf[kk * 193 + row] = tgru_whh[row * DH + ch * 32 + kk];
        }
        __syncthreads();
        for (int kk = 0; kk < 32; ++kk) {
            float wr = wbuf[kk * 193 + lane];
            float wz = wbuf[kk * 193 + 64 + lane];
            float wn = wbuf[kk * 193 + 128 + lane];
            int k = ch * 32 + kk;
            #pragma unroll
            for (int m = 0; m < 8; ++m) {
                float hk = ht[(wave * 8 + m) * DH + k];   // LDS broadcast
                ar[m] = fmaf(wr, hk, ar[m]);
                az[m] = fmaf(wz, hk, az[m]);
                an[m] = fmaf(wn, hk, an[m]);
            }
        }
    }
    // GRU epilogue per i
    #pragma unroll
    for (int m = 0; m < 8; ++m) {
        int il = wave * 8 + m;
        float hval = ht[il * DH + lane];
        float r = sigf(gis[lane] + ar[m] + bhs[lane]);
        float z = sigf(gis[64 + lane] + az[m] + bhs[64 + lane]);
        float n = tanhf(gis[128 + lane] + r * (an[m] + bhs[128 + lane]));
        float th = (1.0f - z) * n + z * hval;
        float kv = kcis[il];
        float nh = (1.0f - kv) * hval + kv * th;
        ws[NHOFF + (size_t)(b * NKC + i0 + il) * DH + lane] = nh;
        dlt[il * DH + lane] = kv * (th - hval);   // delta_h
    }
    __syncthreads();
    // stage fpart_w[:, :64]^T (stride 65, conflict-free)
    for (int idx = t; idx < 4096; idx += 256) {
        int d = idx >> 6, k = idx & 63;
        wbuf[k * 65 + d] = fpart_w[d * 128 + k];
    }
    __syncthreads();
    float acc[8];
    #pragma unroll
    for (int m = 0; m < 8; ++m) acc[m] = 0.f;
    for (int k = 0; k < 64; ++k) {
        float w = wbuf[k * 65 + lane];
        #pragma unroll
        for (int m = 0; m < 8; ++m)
            acc[m] = fmaf(dlt[(wave * 8 + m) * DH + k], w, acc[m]);
    }
    #pragma unroll
    for (int m = 0; m < 8; ++m)
        ws[DPOFF + (size_t)(b * NKC + i0 + wave * 8 + m) * DH + lane] = acc[m];
}

// ---------------------------------------------------------------------------
// K3: partj + outj + kcj + ugru + h_out. grid = 256 blocks (b x 8 j-chunks
// of 16). Static LDS = 63.8 KB; scratch region reused across phases.
// ---------------------------------------------------------------------------
__global__ __launch_bounds__(256) void k3_update(
    const float* __restrict__ ulin_w, const float* __restrict__ ulin_b,
    const float* __restrict__ ugru_wih, const float* __restrict__ ugru_whh,
    const float* __restrict__ ugru_bih, const float* __restrict__ ugru_bhh,
    float* __restrict__ ws, float* __restrict__ out)
{
    int t = threadIdx.x, wave = t >> 6, lane = t & 63;
    int b = blockIdx.x >> 3;
    int j0 = (blockIdx.x & 7) * 16;

    __shared__ float scratch[12352];  // phase a: dpart|wj|ep; b: ulin^T; c: wih^T+whh^T chunks
    __shared__ float pjS[16 * DH];
    __shared__ float outjS[16 * DH];
    __shared__ float newhS[16 * DH];
    __shared__ float kcis[NKC];
    __shared__ float kcjS[16];
    __shared__ float bihS[G3];
    __shared__ float bhhS[G3];

    float* dpartS = scratch;           // 8192  [i*64+d]
    float* wjS    = scratch + 8192;    // 2048  [i*16+jl]
    float* epS    = scratch + 10240;   // 1024  [jl*64+d]

    const float* dp = ws + DPOFF + (size_t)b * NKC * DH;
    for (int idx = t; idx < NKC * DH; idx += 256) dpartS[idx] = dp[idx];
    if (t < NKC) kcis[t] = ws[KCIOFF + b * NKC + t];
    for (int idx = t; idx < 16 * DH; idx += 256) {
        epS[idx]   = ws[EPOFF + j0 * DH + idx];
        newhS[idx] = ws[NHOFF + (size_t)(b * NKC + j0) * DH + idx];
    }
    if (t < G3) { bihS[t] = ugru_bih[t]; bhhS[t] = ugru_bhh[t]; }
    __syncthreads();
    // wj[i,jl] = kci[i] * kc_graph[i, j0+jl]
    for (int idx = t; idx < 2048; idx += 256) {
        int i = idx >> 4, jl = idx & 15;
        wjS[idx] = kcis[i] * ws[KCGOFF + i * NKC + j0 + jl];
    }
    __syncthreads();
    if (t < 16) {  // kcj[jl] = sum_i wj[i,jl]
        float s = 0.f;
        for (int i = 0; i < NKC; ++i) s += wjS[i * 16 + t];
        kcjS[t] = s;
    }
    // phase a: partj — i-loop shared across 4 j per wave
    float ep[4], pa[4];
    #pragma unroll
    for (int q = 0; q < 4; ++q) { ep[q] = epS[(wave + 4 * q) * DH + lane]; pa[q] = 0.f; }
    for (int i = 0; i < NKC; ++i) {
        float dv = dpartS[i * DH + lane];
        #pragma unroll
        for (int q = 0; q < 4; ++q) {
            float pre = fmaxf(dv + ep[q], 0.f);
            pa[q] = fmaf(pre, wjS[i * 16 + wave + 4 * q], pa[q]);
        }
    }
    #pragma unroll
    for (int q = 0; q < 4; ++q) pjS[(wave + 4 * q) * DH + lane] = pa[q];
    __syncthreads();
    // phase b: outj = relu(partj @ ulin_w.T + b)
    float* ulT = scratch;  // 64*65
    for (int idx = t; idx < 4096; idx += 256) {
        int d2 = idx >> 6, k = idx & 63;
        ulT[k * 65 + d2] = ulin_w[d2 * DH + k];
    }
    float ulb = ulin_b[lane];
    __syncthreads();
    #pragma unroll
    for (int q = 0; q < 4; ++q) {
        int jl = wave + 4 * q;
        float a = ulb;
        for (int k = 0; k < DH; ++k) a = fmaf(pjS[jl * DH + k], ulT[k * 65 + lane], a);
        outjS[jl * DH + lane] = fmaxf(a, 0.f);
    }
    // phase c: ugru — both weight matrices k-chunk staged
    float* wihT = scratch;           // 32*193
    float* whhT = scratch + 6176;    // 32*193
    float gir[4], giz[4], gin[4], ghr[4], ghz[4], ghn[4];
    #pragma unroll
    for (int q = 0; q < 4; ++q) { gir[q] = giz[q] = gin[q] = ghr[q] = ghz[q] = ghn[q] = 0.f; }
    for (int ch = 0; ch < 2; ++ch) {
        __syncthreads();   // also covers phase-b reads of ulT/outjS writes
        for (int idx = t; idx < G3 * 32; idx += 256) {
            int row = idx >> 5, kk = idx & 31;
            wihT[kk * 193 + row] = ugru_wih[row * DH + ch * 32 + kk];
            whhT[kk * 193 + row] = ugru_whh[row * DH + ch * 32 + kk];
        }
        __syncthreads();
        for (int kk = 0; kk < 32; ++kk) {
            float wir = wihT[kk * 193 + lane];
            float wiz = wihT[kk * 193 + 64 + lane];
            float win = wihT[kk * 193 + 128 + lane];
            float wwr = whhT[kk * 193 + lane];
            float wwz = whhT[kk * 193 + 64 + lane];
            float wwn = whhT[kk * 193 + 128 + lane];
            int k = ch * 32 + kk;
            #pragma unroll
            for (int q = 0; q < 4; ++q) {
                int jl = wave + 4 * q;
                float ov = outjS[jl * DH + k];
                float nv = newhS[jl * DH + k];
                gir[q] = fmaf(wir, ov, gir[q]);
                giz[q] = fmaf(wiz, ov, giz[q]);
                gin[q] = fmaf(win, ov, gin[q]);
                ghr[q] = fmaf(wwr, nv, ghr[q]);
                ghz[q] = fmaf(wwz, nv, ghz[q]);
                ghn[q] = fmaf(wwn, nv, ghn[q]);
            }
        }
    }
    #pragma unroll
    for (int q = 0; q < 4; ++q) {
        int jl = wave + 4 * q;
        float r = sigf(gir[q] + bihS[lane] + ghr[q] + bhhS[lane]);
        float z = sigf(giz[q] + bihS[64 + lane] + ghz[q] + bhhS[64 + lane]);
        float n = tanhf(gin[q] + bihS[128 + lane] + r * (ghn[q] + bhhS[128 + lane]));
        float nh = newhS[jl * DH + lane];
        float uh = (1.0f - z) * n + z * nh;
        float kj = kcjS[jl];
        out[(size_t)(b * NKC + j0 + jl) * DH + lane] = (1.0f - kj) * nh + kj * uh;
    }
}

extern "C" void kernel_launch(void* const* d_in, const int* in_sizes, int n_in,
                              void* d_out, int out_size, void* d_ws, size_t ws_size,
                              hipStream_t stream) {
    const float* h        = (const float*)d_in[0];
    const float* ex       = (const float*)d_in[1];
    const float* su       = (const float*)d_in[2];
    const float* ex_graph = (const float*)d_in[3];
    const float* kc_gamma = (const float*)d_in[4];
    const float* W_ex     = (const float*)d_in[5];
    const float* W_kc     = (const float*)d_in[6];
    const float* tgru_wih = (const float*)d_in[7];
    const float* tgru_whh = (const float*)d_in[8];
    const float* tgru_bih = (const float*)d_in[9];
    const float* tgru_bhh = (const float*)d_in[10];
    const float* fpart_w  = (const float*)d_in[11];
    const float* fpart_b  = (const float*)d_in[12];
    const float* ulin_w   = (const float*)d_in[13];
    const float* ulin_b   = (const float*)d_in[14];
    const float* ugru_wih = (const float*)d_in[15];
    const float* ugru_whh = (const float*)d_in[16];
    const float* ugru_bih = (const float*)d_in[17];
    const float* ugru_bhh = (const float*)d_in[18];
    float* ws  = (float*)d_ws;
    float* out = (float*)d_out;

    hipLaunchKernelGGL(k1_prep, dim3(37), dim3(256), 0, stream,
                       ex, su, ex_graph, kc_gamma, W_ex, W_kc,
                       tgru_wih, tgru_bih, fpart_w, fpart_b, ws);
    hipLaunchKernelGGL(k2_tgru, dim3(128), dim3(256), 0, stream,
                       h, tgru_whh, tgru_bhh, fpart_w, ws);
    hipLaunchKernelGGL(k3_update, dim3(256), dim3(256), 0, stream,
                       ulin_w, ulin_b, ugru_wih, ugru_whh, ugru_bih, ugru_bhh,
                       ws, out);
}

// Round 2
// 150.198 us; speedup vs baseline: 1.4136x; 1.4136x over previous
//
#include <hip/hip_runtime.h>
#include <math.h>

#define NB  32
#define NKC 128
#define DH  64
#define NEX 1024
#define G3  192

// ws layout (floats)
#define XOFF    0         // 32*64   = 2048
#define KCIOFF  2048      // 32*128  = 4096
#define KCGOFF  6144      // 128*128 = 16384
#define EPOFF   22528     // 128*64  = 8192
#define NHOFF   30720     // 32*128*64 = 262144
#define DPOFF   292864    // 32*128*64 = 262144  (end = 555008 floats = 2.22 MB)

__device__ __forceinline__ float sigf(float x) { return 1.0f / (1.0f + expf(-x)); }

// ---------------------------------------------------------------------------
// K1: x (256 blocks), kci (128 blocks), kc_graph sigmoid (16), epart (4).
// Total grid = 404 blocks x 256 threads. No intra-kernel ordering deps.
// ---------------------------------------------------------------------------
__global__ __launch_bounds__(256) void k1_prep(
    const float* __restrict__ ex, const float* __restrict__ su,
    const float* __restrict__ ex_graph, const float* __restrict__ kc_gamma,
    const float* __restrict__ W_ex, const float* __restrict__ W_kc,
    const float* __restrict__ fpart_w, const float* __restrict__ fpart_b,
    float* __restrict__ ws)
{
    int t = threadIdx.x, wave = t >> 6, lane = t & 63;
    int blk = blockIdx.x;
    __shared__ float kred[256];
    __shared__ float fwT[64 * 65];
    __shared__ float wkS[64 * 33];

    if (blk < 256) {
        // x[b,d] = su*dot(ex, W_ex[d,:1024]) + (1-su)*dot(ex, W_ex[d,1024:])
        int b = blk >> 3;
        int dbase = (blk & 7) * 8;
        float sub = su[b];
        const float* exb = ex + (size_t)b * NEX;
        float er[16];
        #pragma unroll
        for (int i = 0; i < 16; ++i) er[i] = exb[lane + i * 64];
        #pragma unroll
        for (int p = 0; p < 2; ++p) {
            int d = dbase + wave * 2 + p;
            const float* wr = W_ex + (size_t)d * (2 * NEX);
            float a1 = 0.f, a2 = 0.f;
            #pragma unroll
            for (int i = 0; i < 16; ++i) {
                int k = lane + i * 64;
                a1 = fmaf(er[i], wr[k], a1);
                a2 = fmaf(er[i], wr[NEX + k], a2);
            }
            float v = sub * a1 + (1.0f - sub) * a2;
            #pragma unroll
            for (int off = 32; off; off >>= 1) v += __shfl_down(v, off, 64);
            if (lane == 0) ws[XOFF + b * DH + d] = v;
        }
    } else if (blk < 384) {
        // kci[b,i] = dot(ex[b], ex_graph[:,i]); 8 k-slices x 32 i per block
        int q = blk - 256;
        int b = q >> 2, i0 = (q & 3) * 32;
        int i = t & 31, ks = t >> 5;
        const float* exb = ex + (size_t)b * NEX;
        const float* eg = ex_graph + i0 + i;
        int kb = ks * 128;
        float a = 0.f;
        for (int k = 0; k < 128; ++k)
            a = fmaf(exb[kb + k], eg[(size_t)(kb + k) * NKC], a);
        kred[t] = a;
        __syncthreads();
        if (t < 32) {
            float s = 0.f;
            #pragma unroll
            for (int r = 0; r < 8; ++r) s += kred[r * 32 + t];
            ws[KCIOFF + b * NKC + i0 + t] = s;
        }
    } else if (blk < 400) {
        int q = blk - 384;
        #pragma unroll
        for (int r = 0; r < 4; ++r) {
            int idx = q * 1024 + r * 256 + t;
            ws[KCGOFF + idx] = sigf(kc_gamma[idx]);
        }
    } else {
        // epart[j,d] = sum_c W_kc[c,j]*fpart_w[d,64+c] + fpart_b[d]; 32 j/block
        int eb = blk - 400;
        for (int idx = t; idx < 4096; idx += 256) {
            int d = idx >> 6, c = idx & 63;
            fwT[c * 65 + d] = fpart_w[d * 128 + 64 + c];
        }
        for (int idx = t; idx < 2048; idx += 256) {
            int c = idx >> 5, jl = idx & 31;
            wkS[c * 33 + jl] = W_kc[(size_t)c * NKC + eb * 32 + jl];
        }
        __syncthreads();
        float fb = fpart_b[lane];
        #pragma unroll
        for (int q2 = 0; q2 < 8; ++q2) {
            int jl = wave + 4 * q2;
            float a = fb;
            for (int c = 0; c < 64; ++c)
                a = fmaf(wkS[c * 33 + jl], fwT[c * 65 + lane], a);
            ws[EPOFF + (eb * 32 + jl) * DH + lane] = a;
        }
    }
}

// ---------------------------------------------------------------------------
// K2: gi (from x, wave-uniform) + tgru cell + new_h + dpart.
// grid = 128 blocks (b x 4 i-chunks of 32); wave handles 8 i.
// ---------------------------------------------------------------------------
__global__ __launch_bounds__(256) void k2_tgru(
    const float* __restrict__ h, const float* __restrict__ tgru_wih,
    const float* __restrict__ tgru_whh, const float* __restrict__ tgru_bih,
    const float* __restrict__ tgru_bhh, const float* __restrict__ fpart_w,
    float* __restrict__ ws)
{
    int t = threadIdx.x, wave = t >> 6, lane = t & 63;
    int b = blockIdx.x >> 2;
    int i0 = (blockIdx.x & 3) * 32;
    __shared__ float whhT[32 * 193];   // reused for fpart_w^T (64*65) later
    __shared__ float wihT[32 * 193];
    __shared__ float ht[32 * DH];
    __shared__ float dlt[32 * DH];
    __shared__ float xs[DH];
    __shared__ float bih3[G3];
    __shared__ float bhh3[G3];
    __shared__ float kcis[32];

    const float* hb = h + (size_t)(b * NKC + i0) * DH;
    for (int idx = t; idx < 32 * DH; idx += 256) ht[idx] = hb[idx];
    if (t < DH) xs[t] = ws[XOFF + b * DH + t];
    if (t < G3) { bih3[t] = tgru_bih[t]; bhh3[t] = tgru_bhh[t]; }
    if (t < 32) kcis[t] = ws[KCIOFF + b * NKC + i0 + t];
    __syncthreads();

    float gir = bih3[lane], giz = bih3[64 + lane], gin = bih3[128 + lane];
    float ar[8], az[8], an[8];
    #pragma unroll
    for (int m = 0; m < 8; ++m) {
        ar[m] = bhh3[lane]; az[m] = bhh3[64 + lane]; an[m] = bhh3[128 + lane];
    }

    for (int ch = 0; ch < 2; ++ch) {
        __syncthreads();
        for (int idx = t; idx < G3 * 32; idx += 256) {
            int row = idx >> 5, kk = idx & 31;
            whhT[kk * 193 + row] = tgru_whh[row * DH + ch * 32 + kk];
            wihT[kk * 193 + row] = tgru_wih[row * DH + ch * 32 + kk];
        }
        __syncthreads();
        for (int kk = 0; kk < 32; ++kk) {
            float wr = whhT[kk * 193 + lane];
            float wz = whhT[kk * 193 + 64 + lane];
            float wn = whhT[kk * 193 + 128 + lane];
            float xk = xs[ch * 32 + kk];
            gir = fmaf(wihT[kk * 193 + lane], xk, gir);
            giz = fmaf(wihT[kk * 193 + 64 + lane], xk, giz);
            gin = fmaf(wihT[kk * 193 + 128 + lane], xk, gin);
            int k = ch * 32 + kk;
            #pragma unroll
            for (int m = 0; m < 8; ++m) {
                float hk = ht[(wave * 8 + m) * DH + k];   // LDS broadcast
                ar[m] = fmaf(wr, hk, ar[m]);
                az[m] = fmaf(wz, hk, az[m]);
                an[m] = fmaf(wn, hk, an[m]);
            }
        }
    }
    // GRU epilogue per i
    #pragma unroll
    for (int m = 0; m < 8; ++m) {
        int il = wave * 8 + m;
        float hval = ht[il * DH + lane];
        float r = sigf(gir + ar[m]);
        float z = sigf(giz + az[m]);
        float n = tanhf(gin + r * an[m]);
        float th = (1.0f - z) * n + z * hval;
        float kv = kcis[il];
        float nh = (1.0f - kv) * hval + kv * th;
        ws[NHOFF + (size_t)(b * NKC + i0 + il) * DH + lane] = nh;
        dlt[il * DH + lane] = kv * (th - hval);   // delta_h
    }
    __syncthreads();
    // dpart = delta_h @ fpart_w[:, :64].T ; stage fpart_w^T (stride 65)
    for (int idx = t; idx < 4096; idx += 256) {
        int d = idx >> 6, k = idx & 63;
        whhT[k * 65 + d] = fpart_w[d * 128 + k];
    }
    __syncthreads();
    float acc[8];
    #pragma unroll
    for (int m = 0; m < 8; ++m) acc[m] = 0.f;
    for (int k = 0; k < 64; ++k) {
        float w = whhT[k * 65 + lane];
        #pragma unroll
        for (int m = 0; m < 8; ++m)
            acc[m] = fmaf(dlt[(wave * 8 + m) * DH + k], w, acc[m]);
    }
    #pragma unroll
    for (int m = 0; m < 8; ++m)
        ws[DPOFF + (size_t)(b * NKC + i0 + wave * 8 + m) * DH + lane] = acc[m];
}

// ---------------------------------------------------------------------------
// K3: partj + outj + kcj + ugru + h_out. grid = 256 blocks (b x 8 j-chunks
// of 16). Scratch LDS region reused across phases.
// ---------------------------------------------------------------------------
__global__ __launch_bounds__(256) void k3_update(
    const float* __restrict__ ulin_w, const float* __restrict__ ulin_b,
    const float* __restrict__ ugru_wih, const float* __restrict__ ugru_whh,
    const float* __restrict__ ugru_bih, const float* __restrict__ ugru_bhh,
    float* __restrict__ ws, float* __restrict__ out)
{
    int t = threadIdx.x, wave = t >> 6, lane = t & 63;
    int b = blockIdx.x >> 3;
    int j0 = (blockIdx.x & 7) * 16;

    __shared__ float scratch[12352];  // a: dpart|wj|ep; b: ulin^T; c: wih^T+whh^T
    __shared__ float pjS[16 * DH];
    __shared__ float outjS[16 * DH];
    __shared__ float newhS[16 * DH];
    __shared__ float kcis[NKC];
    __shared__ float kcjS[16];
    __shared__ float bihS[G3];
    __shared__ float bhhS[G3];

    float* dpartS = scratch;           // 8192  [i*64+d]
    float* wjS    = scratch + 8192;    // 2048  [i*16+jl]
    float* epS    = scratch + 10240;   // 1024  [jl*64+d]

    const float* dp = ws + DPOFF + (size_t)b * NKC * DH;
    for (int idx = t; idx < NKC * DH; idx += 256) dpartS[idx] = dp[idx];
    if (t < NKC) kcis[t] = ws[KCIOFF + b * NKC + t];
    for (int idx = t; idx < 16 * DH; idx += 256) {
        epS[idx]   = ws[EPOFF + j0 * DH + idx];
        newhS[idx] = ws[NHOFF + (size_t)(b * NKC + j0) * DH + idx];
    }
    if (t < G3) { bihS[t] = ugru_bih[t]; bhhS[t] = ugru_bhh[t]; }
    __syncthreads();
    // wj[i,jl] = kci[i] * kc_graph[i, j0+jl]
    for (int idx = t; idx < 2048; idx += 256) {
        int i = idx >> 4, jl = idx & 15;
        wjS[idx] = kcis[i] * ws[KCGOFF + i * NKC + j0 + jl];
    }
    __syncthreads();
    if (t < 16) {  // kcj[jl] = sum_i wj[i,jl]
        float s = 0.f;
        for (int i = 0; i < NKC; ++i) s += wjS[i * 16 + t];
        kcjS[t] = s;
    }
    // phase a: partj — i-loop shared across 4 j per wave
    float ep[4], pa[4];
    #pragma unroll
    for (int q = 0; q < 4; ++q) { ep[q] = epS[(wave + 4 * q) * DH + lane]; pa[q] = 0.f; }
    for (int i = 0; i < NKC; ++i) {
        float dv = dpartS[i * DH + lane];
        #pragma unroll
        for (int q = 0; q < 4; ++q) {
            float pre = fmaxf(dv + ep[q], 0.f);
            pa[q] = fmaf(pre, wjS[i * 16 + wave + 4 * q], pa[q]);
        }
    }
    #pragma unroll
    for (int q = 0; q < 4; ++q) pjS[(wave + 4 * q) * DH + lane] = pa[q];
    __syncthreads();
    // phase b: outj = relu(partj @ ulin_w.T + b)
    float* ulT = scratch;  // 64*65
    for (int idx = t; idx < 4096; idx += 256) {
        int d2 = idx >> 6, k = idx & 63;
        ulT[k * 65 + d2] = ulin_w[d2 * DH + k];
    }
    float ulb = ulin_b[lane];
    __syncthreads();
    #pragma unroll
    for (int q = 0; q < 4; ++q) {
        int jl = wave + 4 * q;
        float a = ulb;
        for (int k = 0; k < DH; ++k) a = fmaf(pjS[jl * DH + k], ulT[k * 65 + lane], a);
        outjS[jl * DH + lane] = fmaxf(a, 0.f);
    }
    // phase c: ugru — both weight matrices k-chunk staged
    float* wihT = scratch;           // 32*193
    float* whhT = scratch + 6176;    // 32*193
    float gir[4], giz[4], gin[4], ghr[4], ghz[4], ghn[4];
    #pragma unroll
    for (int q = 0; q < 4; ++q) { gir[q] = giz[q] = gin[q] = ghr[q] = ghz[q] = ghn[q] = 0.f; }
    for (int ch = 0; ch < 2; ++ch) {
        __syncthreads();   // also covers phase-b reads of ulT before overwrite
        for (int idx = t; idx < G3 * 32; idx += 256) {
            int row = idx >> 5, kk = idx & 31;
            wihT[kk * 193 + row] = ugru_wih[row * DH + ch * 32 + kk];
            whhT[kk * 193 + row] = ugru_whh[row * DH + ch * 32 + kk];
        }
        __syncthreads();
        for (int kk = 0; kk < 32; ++kk) {
            float wir = wihT[kk * 193 + lane];
            float wiz = wihT[kk * 193 + 64 + lane];
            float win = wihT[kk * 193 + 128 + lane];
            float wwr = whhT[kk * 193 + lane];
            float wwz = whhT[kk * 193 + 64 + lane];
            float wwn = whhT[kk * 193 + 128 + lane];
            int k = ch * 32 + kk;
            #pragma unroll
            for (int q = 0; q < 4; ++q) {
                int jl = wave + 4 * q;
                float ov = outjS[jl * DH + k];
                float nv = newhS[jl * DH + k];
                gir[q] = fmaf(wir, ov, gir[q]);
                giz[q] = fmaf(wiz, ov, giz[q]);
                gin[q] = fmaf(win, ov, gin[q]);
                ghr[q] = fmaf(wwr, nv, ghr[q]);
                ghz[q] = fmaf(wwz, nv, ghz[q]);
                ghn[q] = fmaf(wwn, nv, ghn[q]);
            }
        }
    }
    #pragma unroll
    for (int q = 0; q < 4; ++q) {
        int jl = wave + 4 * q;
        float r = sigf(gir[q] + bihS[lane] + ghr[q] + bhhS[lane]);
        float z = sigf(giz[q] + bihS[64 + lane] + ghz[q] + bhhS[64 + lane]);
        float n = tanhf(gin[q] + bihS[128 + lane] + r * (ghn[q] + bhhS[128 + lane]));
        float nh = newhS[jl * DH + lane];
        float uh = (1.0f - z) * n + z * nh;
        float kj = kcjS[jl];
        out[(size_t)(b * NKC + j0 + jl) * DH + lane] = (1.0f - kj) * nh + kj * uh;
    }
}

extern "C" void kernel_launch(void* const* d_in, const int* in_sizes, int n_in,
                              void* d_out, int out_size, void* d_ws, size_t ws_size,
                              hipStream_t stream) {
    const float* h        = (const float*)d_in[0];
    const float* ex       = (const float*)d_in[1];
    const float* su       = (const float*)d_in[2];
    const float* ex_graph = (const float*)d_in[3];
    const float* kc_gamma = (const float*)d_in[4];
    const float* W_ex     = (const float*)d_in[5];
    const float* W_kc     = (const float*)d_in[6];
    const float* tgru_wih = (const float*)d_in[7];
    const float* tgru_whh = (const float*)d_in[8];
    const float* tgru_bih = (const float*)d_in[9];
    const float* tgru_bhh = (const float*)d_in[10];
    const float* fpart_w  = (const float*)d_in[11];
    const float* fpart_b  = (const float*)d_in[12];
    const float* ulin_w   = (const float*)d_in[13];
    const float* ulin_b   = (const float*)d_in[14];
    const float* ugru_wih = (const float*)d_in[15];
    const float* ugru_whh = (const float*)d_in[16];
    const float* ugru_bih = (const float*)d_in[17];
    const float* ugru_bhh = (const float*)d_in[18];
    float* ws  = (float*)d_ws;
    float* out = (float*)d_out;

    hipLaunchKernelGGL(k1_prep, dim3(404), dim3(256), 0, stream,
                       ex, su, ex_graph, kc_gamma, W_ex, W_kc,
                       fpart_w, fpart_b, ws);
    hipLaunchKernelGGL(k2_tgru, dim3(128), dim3(256), 0, stream,
                       h, tgru_wih, tgru_whh, tgru_bih, tgru_bhh, fpart_w, ws);
    hipLaunchKernelGGL(k3_update, dim3(256), dim3(256), 0, stream,
                       ulin_w, ulin_b, ugru_wih, ugru_whh, ugru_bih, ugru_bhh,
                       ws, out);
}